// Round 5
// baseline (11390.199 us; speedup 1.0000x reference)
//
#include <hip/hip_runtime.h>
#include <hip/hip_fp16.h>
#include <math.h>

// Problem constants
#define BATCH 256
#define TSEQ  512
#define FEAT  64
#define NU1   256
#define NU2   128

// half2-element offsets of packed fp16 weight planes inside d_ws.
// Quad-pair planes, K-split-contiguous chunk order (one chunk = 4 half2 row-pairs):
// GRU1 plane (per gate): [4 kq][10 chunks][256 cols][4]
//   chunks 0..1 = x rows  (kq quarter: feats kq*16..kq*16+15  = act1 pairs kq*8+0..7)
//   chunks 2..9 = h1 rows (kq quarter: units kq*64..kq*64+63  = act1 pairs 32+kq*32+0..31)
// GRU2 plane (per gate): [8 ko][6 chunks][128 cols][4]
//   chunks 0..3 = h1 rows (ko eighth: units ko*32..ko*32+31   = act1 pairs 32+ko*16+0..15)
//   chunks 4..5 = h2 rows (ko eighth: units ko*16..ko*16+15   = act2 pairs ko*8+0..7)
#define G1Z_OFF 0
#define G1R_OFF 40960
#define G1H_OFF 81920
#define G2Z_OFF 122880
#define G2R_OFF 147456
#define G2H_OFF 172032
#define TOTAL_H2 196608   // 786,432 bytes of d_ws

// uint4-unit plane offsets (half2 offset / 4)
#define G1Z_U4 0
#define G1R_U4 10240
#define G1H_U4 20480
#define G2Z_U4 30720
#define G2R_U4 36864
#define G2H_U4 43008

typedef _Float16 h2f __attribute__((ext_vector_type(2)));

__device__ __forceinline__ float sigmoid_f(float v) {
    return 1.0f / (1.0f + __expf(-v));
}
__device__ __forceinline__ float tanh_f(float v) {
    float c = fminf(fmaxf(v, -15.0f), 15.0f);
    float e = __expf(2.0f * c);
    return (e - 1.0f) / (e + 1.0f);
}

__device__ __forceinline__ h2f bch2(unsigned int u) {
    return __builtin_bit_cast(h2f, u);
}
__device__ __forceinline__ unsigned int pack2(float a, float b) {
    h2f v;
    v.x = (_Float16)a;
    v.y = (_Float16)b;
    return __builtin_bit_cast(unsigned int, v);
}

// acc += dot of 4 half2 pairs (8 fp16 weights x 8 fp16 activations), fp32 accum
__device__ __forceinline__ void dot4(float& acc, uint4 w, uint4 a) {
    acc = __builtin_amdgcn_fdot2(bch2(w.x), bch2(a.x), acc, false);
    acc = __builtin_amdgcn_fdot2(bch2(w.y), bch2(a.y), acc, false);
    acc = __builtin_amdgcn_fdot2(bch2(w.z), bch2(a.z), acc, false);
    acc = __builtin_amdgcn_fdot2(bch2(w.w), bch2(a.w), acc, false);
}

// ---------------- weight packing (fp32 -> fp16 quad-pair planes) ----------------
__global__ void pack_weights(const float* __restrict__ k1, const float* __restrict__ r1,
                             const float* __restrict__ k2, const float* __restrict__ r2,
                             __half2* __restrict__ ws)
{
    int idx = blockIdx.x * 256 + threadIdx.x;
    if (idx >= TOTAL_H2) return;
    float a, b;
    if (idx < G2Z_OFF) {
        // GRU1 planes: 3 x [4 kq][10 chunks][256 cols][4]
        int plane = idx / 40960;       // 0=z 1=r 2=h
        int rem   = idx % 40960;       // = cc*1024 + col*4 + q
        int cc    = rem >> 10;         // 0..39
        int col   = (rem >> 2) & 255;
        int q     = rem & 3;
        int kq    = cc / 10;
        int c     = cc - kq * 10;
        int g     = plane * 256 + col; // gate-column in [0,768)
        int pair  = (c < 2) ? (kq * 8 + c * 4 + q)
                            : (32 + kq * 32 + (c - 2) * 4 + q);
        int row0  = pair * 2;
        if (row0 < 64) { a = k1[row0 * 768 + g];        b = k1[(row0 + 1) * 768 + g]; }
        else           { a = r1[(row0 - 64) * 768 + g]; b = r1[(row0 - 63) * 768 + g]; }
    } else {
        // GRU2 planes: 3 x [8 ko][6 chunks][128 cols][4]
        int idx2  = idx - G2Z_OFF;
        int plane = idx2 / 24576;
        int rem   = idx2 % 24576;      // = cc*512 + col*4 + q
        int cc    = rem >> 9;          // 0..47
        int col   = (rem >> 2) & 127;
        int q     = rem & 3;
        int ko    = cc / 6;
        int c     = cc - ko * 6;
        int g     = plane * 128 + col; // gate-column in [0,384)
        int pair  = (c < 4) ? (ko * 16 + c * 4 + q)
                            : (128 + ko * 8 + (c - 4) * 4 + q);
        int row0  = pair * 2;
        if (row0 < 256) { a = k2[row0 * 384 + g];         b = k2[(row0 + 1) * 384 + g]; }
        else            { a = r2[(row0 - 256) * 384 + g]; b = r2[(row0 - 255) * 384 + g]; }
    }
    __half2 h;
    h.x = __float2half_rn(a);
    h.y = __float2half_rn(b);
    ws[idx] = h;
}

// K-segment over NCH chunks (NCH % 4 == 0): 3 gate streams, NAMED A/B double
// buffer (2 chunks each), runtime #pragma unroll 1 loop so the scheduler cannot
// hoist the whole stream and spill (R1/R2 lesson: full unroll -> 256 VGPR +
// 18.9 GB scratch). Proven structure from R3 (no spill at 128-VGPR budget).
template <int COLS, int NCH>
__device__ __forceinline__ void seg3(const uint4* __restrict__ pz,
                                     const uint4* __restrict__ pr,
                                     const uint4* __restrict__ ph,
                                     const unsigned int* __restrict__ act,
                                     float& az, float& ar, float& a3)
{
    static_assert(NCH % 4 == 0, "NCH must be a multiple of 4");
    // buffer A holds chunks c,c+1 ; buffer B holds chunks c+2,c+3
    uint4 a_z0 = pz[0], a_z1 = pz[COLS];
    uint4 a_r0 = pr[0], a_r1 = pr[COLS];
    uint4 a_h0 = ph[0], a_h1 = ph[COLS];
    #pragma unroll 1
    for (int c = 0; c < NCH; c += 4) {
        const uint4* qz = pz + 2 * COLS;
        const uint4* qr = pr + 2 * COLS;
        const uint4* qh = ph + 2 * COLS;
        uint4 b_z0 = qz[0], b_z1 = qz[COLS];
        uint4 b_r0 = qr[0], b_r1 = qr[COLS];
        uint4 b_h0 = qh[0], b_h1 = qh[COLS];
        const uint4 v0 = *(const uint4*)(act);
        const uint4 v1 = *(const uint4*)(act + 4);
        dot4(az, a_z0, v0); dot4(ar, a_r0, v0); dot4(a3, a_h0, v0);
        dot4(az, a_z1, v1); dot4(ar, a_r1, v1); dot4(a3, a_h1, v1);
        pz += 4 * COLS; pr += 4 * COLS; ph += 4 * COLS;
        if (c + 4 < NCH) {   // prefetch next A (chunks c+4,c+5); no OOB on last iter
            a_z0 = pz[0]; a_z1 = pz[COLS];
            a_r0 = pr[0]; a_r1 = pr[COLS];
            a_h0 = ph[0]; a_h1 = ph[COLS];
        }
        const uint4 v2 = *(const uint4*)(act + 8);
        const uint4 v3 = *(const uint4*)(act + 12);
        act += 16;
        dot4(az, b_z0, v2); dot4(ar, b_r0, v2); dot4(a3, b_h0, v2);
        dot4(az, b_z1, v3); dot4(ar, b_r1, v3); dot4(a3, b_h1, v3);
    }
}

// 2-chunk straight-line tail segment (x-part of GRU1, h2-part of GRU2)
template <int COLS>
__device__ __forceinline__ void seg_pair(const uint4* __restrict__ pz,
                                         const uint4* __restrict__ pr,
                                         const uint4* __restrict__ ph,
                                         const unsigned int* __restrict__ act,
                                         float& az, float& ar, float& a3)
{
    uint4 z0 = pz[0], z1 = pz[COLS];
    uint4 r0 = pr[0], r1 = pr[COLS];
    uint4 h0 = ph[0], h1 = ph[COLS];
    const uint4 v0 = *(const uint4*)(act);
    const uint4 v1 = *(const uint4*)(act + 4);
    dot4(az, z0, v0); dot4(ar, r0, v0); dot4(a3, h0, v0);
    dot4(az, z1, v1); dot4(ar, r1, v1); dot4(a3, h1, v1);
}

// 256 WGs x 1024 threads, one batch row per WG.
// waves_per_eu PINNED to (4,4): R4 lesson — without the max, the allocator
// squeezes to 64 VGPR chasing 2 WGs/CU (unreachable: grid=1 WG/CU), spilling
// 2.5 KB/thread -> 640 MB scratch -> 28.8 GB HBM fetch. Pin gives 128 VGPRs.
// K-split: GRU1 by 4 (kq = tid&3), GRU2 by 8 (ko = tid&7); shfl_xor reduce.
// One barrier per timestep.
__global__ void
__attribute__((amdgpu_flat_work_group_size(1024, 1024)))
__attribute__((amdgpu_waves_per_eu(4, 4)))
gru_fused(const float* __restrict__ x,
          const float* __restrict__ b1, const float* __restrict__ b2,
          const float* __restrict__ w3, const float* __restrict__ b3,
          const float* __restrict__ w4, const float* __restrict__ b4,
          const float* __restrict__ w5, const float* __restrict__ b5,
          const unsigned int* __restrict__ wp,
          float* __restrict__ out)
{
    // fp16 activation pair buffers (uint = one half2), double-buffered.
    // act1: pairs [0..31] = x(t) (64 feats), pairs [32..159] = h1 (256 units)
    // act2: pairs [0..63] = h2 (128 units)
    __shared__ __align__(16) unsigned int act1[2][160];
    __shared__ __align__(16) unsigned int act2[2][64];
    __shared__ float h2fin[NU2];
    __shared__ float d3[64];
    __shared__ float d4[32];

    const int tid = threadIdx.x;
    const int row = blockIdx.x;
    const int j   = tid >> 2;       // GRU1 column (0..255)
    const int kq  = tid & 3;        // GRU1 K-quarter
    const int c2  = tid >> 3;       // GRU2 column (0..127)
    const int ko  = tid & 7;        // GRU2 K-eighth

    for (int i = tid; i < 2 * 160; i += 1024) (&act1[0][0])[i] = 0u;
    for (int i = tid; i < 2 * 64;  i += 1024) (&act2[0][0])[i] = 0u;

    // GRU1 biases (z,r folded; h kept split for reset_after), counted once via kq mask
    const float bm1  = (kq == 0) ? 1.0f : 0.0f;
    const float bz1  = (b1[j] + b1[768 + j]) * bm1;
    const float br1  = (b1[256 + j] + b1[1024 + j]) * bm1;
    const float bxh1 = b1[512 + j] * bm1;
    const float brh1 = b1[1280 + j] * bm1;
    // GRU2 biases, counted once via ko mask
    const float bm2  = (ko == 0) ? 1.0f : 0.0f;
    const float bz2  = (b2[c2] + b2[384 + c2]) * bm2;
    const float br2  = (b2[128 + c2] + b2[512 + c2]) * bm2;
    const float bxh2 = b2[256 + c2] * bm2;
    const float brh2 = b2[640 + c2] * bm2;

    const uint4* wp4 = (const uint4*)wp;
    const uint4* g1z = wp4 + G1Z_U4 + (kq * 10) * 256 + j;
    const uint4* g1r = wp4 + G1R_U4 + (kq * 10) * 256 + j;
    const uint4* g1h = wp4 + G1H_U4 + (kq * 10) * 256 + j;
    const uint4* g2z = wp4 + G2Z_U4 + (ko * 6) * 128 + c2;
    const uint4* g2r = wp4 + G2R_U4 + (ko * 6) * 128 + c2;
    const uint4* g2h = wp4 + G2H_U4 + (ko * 6) * 128 + c2;

    __syncthreads();   // zeros visible before x(0) pack overwrites x-part

    if (tid < FEAT) {
        float x0 = x[(size_t)row * TSEQ * FEAT + tid];
        float xb = __shfl_xor(x0, 1);
        if ((tid & 1) == 0) act1[0][tid >> 1] = pack2(x0, xb);
    }
    __syncthreads();

    float hp1 = 0.0f;   // h1 previous state, col j (redundant on the lane quad)
    float hp2 = 0.0f;   // h2 previous state, col c2 (redundant on the lane octet)

    for (int t = 0; t < TSEQ; ++t) {
        const int cur = t & 1, nb = cur ^ 1;

        // prefetch next x into registers (packed to LDS before the barrier)
        float xpre = 0.0f;
        if (t + 1 < TSEQ && tid < FEAT)
            xpre = x[(size_t)row * TSEQ * FEAT + (t + 1) * FEAT + tid];

        // ---------------- GRU1: reads act1[cur]; writes act1[nb] ----------------
        float az = bz1, ar = br1, aA = bxh1, aB = brh1;
        seg_pair<256>(g1z, g1r, g1h, &act1[cur][kq * 8], az, ar, aA);
        seg3<256, 8>(g1z + 2 * 256, g1r + 2 * 256, g1h + 2 * 256,
                     &act1[cur][32 + kq * 32], az, ar, aB);
        az += __shfl_xor(az, 1); az += __shfl_xor(az, 2);
        ar += __shfl_xor(ar, 1); ar += __shfl_xor(ar, 2);
        aA += __shfl_xor(aA, 1); aA += __shfl_xor(aA, 2);
        aB += __shfl_xor(aB, 1); aB += __shfl_xor(aB, 2);
        {
            const float z  = sigmoid_f(az);
            const float rg = sigmoid_f(ar);
            const float hh = tanh_f(aA + rg * aB);
            const float hn = z * hp1 + (1.0f - z) * hh;
            hp1 = hn;
            const float hnb = __shfl_xor(hn, 4);   // partner column (2m+1) on lane 8m
            if ((tid & 7) == 0) act1[nb][32 + (tid >> 3)] = pack2(hn, hnb);
        }
        if (t + 1 < TSEQ && tid < FEAT) {
            float xb = __shfl_xor(xpre, 1);
            if ((tid & 1) == 0) act1[nb][tid >> 1] = pack2(xpre, xb);
        }
        __syncthreads();   // THE one barrier: act1[nb] (h1(t) + x(t+1)) visible

        // ---------------- GRU2: reads act1[nb] h-part, act2[cur]; writes act2[nb] ----------------
        float az2 = bz2, ar2 = br2, aA2 = bxh2, aB2 = brh2;
        seg3<128, 4>(g2z, g2r, g2h, &act1[nb][32 + ko * 16], az2, ar2, aA2);
        seg_pair<128>(g2z + 4 * 128, g2r + 4 * 128, g2h + 4 * 128,
                      &act2[cur][ko * 8], az2, ar2, aB2);
        az2 += __shfl_xor(az2, 1); az2 += __shfl_xor(az2, 2); az2 += __shfl_xor(az2, 4);
        ar2 += __shfl_xor(ar2, 1); ar2 += __shfl_xor(ar2, 2); ar2 += __shfl_xor(ar2, 4);
        aA2 += __shfl_xor(aA2, 1); aA2 += __shfl_xor(aA2, 2); aA2 += __shfl_xor(aA2, 4);
        aB2 += __shfl_xor(aB2, 1); aB2 += __shfl_xor(aB2, 2); aB2 += __shfl_xor(aB2, 4);
        {
            const float z2v = sigmoid_f(az2);
            const float rg2 = sigmoid_f(ar2);
            const float hh2 = tanh_f(aA2 + rg2 * aB2);
            const float hn2 = z2v * hp2 + (1.0f - z2v) * hh2;
            hp2 = hn2;
            const float hnb2 = __shfl_xor(hn2, 8); // partner column (2m+1) on lane 16m
            if ((tid & 15) == 0) act2[nb][tid >> 4] = pack2(hn2, hnb2);
        }
        // no second barrier: next step's barrier covers act2[nb] visibility;
        // all WAR hazards are buffer-separated (same discipline as proven kernel)
    }

    if ((tid & 7) == 0) h2fin[c2] = hp2;   // final h2 state, fp32
    __syncthreads();

    // ---------------- dense head: h2 -> 64 -> 32 -> 24 ----------------
    if (tid < 64) {
        float a = b3[tid];
        #pragma unroll 4
        for (int u = 0; u < NU2; ++u) a += h2fin[u] * w3[u * 64 + tid];
        d3[tid] = a;
    }
    __syncthreads();
    if (tid < 32) {
        float a = b4[tid];
        #pragma unroll 4
        for (int u = 0; u < 64; ++u) a += d3[u] * w4[u * 32 + tid];
        d4[tid] = a;
    }
    __syncthreads();
    if (tid < 24) {
        float a = b5[tid];
        #pragma unroll 4
        for (int u = 0; u < 32; ++u) a += d4[u] * w5[u * 24 + tid];
        out[(size_t)row * 24 + tid] = a;
    }
}

extern "C" void kernel_launch(void* const* d_in, const int* in_sizes, int n_in,
                              void* d_out, int out_size, void* d_ws, size_t ws_size,
                              hipStream_t stream) {
    (void)in_sizes; (void)n_in; (void)ws_size; (void)out_size;
    const float* x  = (const float*)d_in[0];
    const float* k1 = (const float*)d_in[1];
    const float* r1 = (const float*)d_in[2];
    const float* b1 = (const float*)d_in[3];
    const float* k2 = (const float*)d_in[4];
    const float* r2 = (const float*)d_in[5];
    const float* b2 = (const float*)d_in[6];
    const float* w3 = (const float*)d_in[7];
    const float* b3 = (const float*)d_in[8];
    const float* w4 = (const float*)d_in[9];
    const float* b4 = (const float*)d_in[10];
    const float* w5 = (const float*)d_in[11];
    const float* b5 = (const float*)d_in[12];
    float* out = (float*)d_out;

    hipLaunchKernelGGL(pack_weights, dim3((TOTAL_H2 + 255) / 256), dim3(256), 0, stream,
                       k1, r1, k2, r2, (__half2*)d_ws);
    hipLaunchKernelGGL(gru_fused, dim3(BATCH), dim3(1024), 0, stream,
                       x, b1, b2, w3, b3, w4, b4, w5, b5,
                       (const unsigned int*)d_ws, out);
}

// Round 6
// 11285.943 us; speedup vs baseline: 1.0092x; 1.0092x over previous
//
#include <hip/hip_runtime.h>
#include <hip/hip_fp16.h>
#include <math.h>

// Problem constants
#define BATCH 256
#define TSEQ  512
#define FEAT  64
#define NU1   256
#define NU2   128

// half2-element offsets of packed fp16 weight planes inside d_ws.
// Quad-pair planes, K-split-contiguous chunk order (one chunk = 4 half2 row-pairs):
// GRU1 plane (per gate): [2 kh][20 chunks][256 cols][4]
//   chunks 0..3  = x rows (kh half: feats kh*32..kh*32+31  = act1 pairs kh*16+0..15)
//   chunks 4..19 = h1 rows (kh half: units kh*128..kh*128+127 = act1 pairs 32+kh*64+0..63)
// GRU2 plane (per gate): [4 kq][12 chunks][128 cols][4]
//   chunks 0..7  = h1 rows (kq quarter: units kq*64..kq*64+63 = act1 pairs 32+kq*32+0..31)
//   chunks 8..11 = h2 rows (kq quarter: units kq*32..kq*32+31 = act2 pairs kq*16+0..15)
#define G1Z_OFF 0
#define G1R_OFF 40960
#define G1H_OFF 81920
#define G2Z_OFF 122880
#define G2R_OFF 147456
#define G2H_OFF 172032
#define TOTAL_H2 196608   // 786,432 bytes of d_ws

// uint4-unit plane offsets (half2 offset / 4)
#define G1Z_U4 0
#define G1R_U4 10240
#define G1H_U4 20480
#define G2Z_U4 30720
#define G2R_U4 36864
#define G2H_U4 43008

typedef _Float16 h2f __attribute__((ext_vector_type(2)));

__device__ __forceinline__ float sigmoid_f(float v) {
    return 1.0f / (1.0f + __expf(-v));
}
__device__ __forceinline__ float tanh_f(float v) {
    float c = fminf(fmaxf(v, -15.0f), 15.0f);
    float e = __expf(2.0f * c);
    return (e - 1.0f) / (e + 1.0f);
}

__device__ __forceinline__ h2f bch2(unsigned int u) {
    return __builtin_bit_cast(h2f, u);
}
__device__ __forceinline__ unsigned int pack2(float a, float b) {
    h2f v;
    v.x = (_Float16)a;
    v.y = (_Float16)b;
    return __builtin_bit_cast(unsigned int, v);
}

// acc += dot of 4 half2 pairs (8 fp16 weights x 8 fp16 activations), fp32 accum
__device__ __forceinline__ void dot4(float& acc, uint4 w, uint4 a) {
    acc = __builtin_amdgcn_fdot2(bch2(w.x), bch2(a.x), acc, false);
    acc = __builtin_amdgcn_fdot2(bch2(w.y), bch2(a.y), acc, false);
    acc = __builtin_amdgcn_fdot2(bch2(w.z), bch2(a.z), acc, false);
    acc = __builtin_amdgcn_fdot2(bch2(w.w), bch2(a.w), acc, false);
}

// ---------------- weight packing (fp32 -> fp16 quad-pair planes) ----------------
// R3-proven layout: GRU1 [2 kh][20 chunks], GRU2 [4 kq][12 chunks].
__global__ void pack_weights(const float* __restrict__ k1, const float* __restrict__ r1,
                             const float* __restrict__ k2, const float* __restrict__ r2,
                             __half2* __restrict__ ws)
{
    int idx = blockIdx.x * 256 + threadIdx.x;
    if (idx >= TOTAL_H2) return;
    float a, b;
    if (idx < G2Z_OFF) {
        // GRU1 planes: 3 x [2 kh][20 chunks][256 cols][4]
        int plane = idx / 40960;       // 0=z 1=r 2=h
        int rem   = idx % 40960;       // = cc*1024 + col*4 + q
        int cc    = rem >> 10;         // 0..39
        int col   = (rem >> 2) & 255;
        int q     = rem & 3;
        int kh    = cc / 20;
        int c     = cc - kh * 20;
        int g     = plane * 256 + col; // gate-column in [0,768)
        int pair  = (c < 4) ? ((kh * 4 + c) * 4 + q)
                            : (32 + (kh * 16 + (c - 4)) * 4 + q);
        int row0  = pair * 2;
        if (row0 < 64) { a = k1[row0 * 768 + g];        b = k1[(row0 + 1) * 768 + g]; }
        else           { a = r1[(row0 - 64) * 768 + g]; b = r1[(row0 - 63) * 768 + g]; }
    } else {
        // GRU2 planes: 3 x [4 kq][12 chunks][128 cols][4]
        int idx2  = idx - G2Z_OFF;
        int plane = idx2 / 24576;
        int rem   = idx2 % 24576;      // = cc*512 + col*4 + q
        int cc    = rem >> 9;          // 0..47
        int col   = (rem >> 2) & 127;
        int q     = rem & 3;
        int kq    = cc / 12;
        int c     = cc - kq * 12;
        int g     = plane * 128 + col; // gate-column in [0,384)
        int pair  = (c < 8) ? ((kq * 8 + c) * 4 + q)
                            : (128 + (kq * 4 + (c - 8)) * 4 + q);
        int row0  = pair * 2;
        if (row0 < 256) { a = k2[row0 * 384 + g];         b = k2[(row0 + 1) * 384 + g]; }
        else            { a = r2[(row0 - 256) * 384 + g]; b = r2[(row0 - 255) * 384 + g]; }
    }
    __half2 h;
    h.x = __float2half_rn(a);
    h.y = __float2half_rn(b);
    ws[idx] = h;
}

// 2-deep K-segment (NCH % 4 == 0): 3 gate streams, NAMED A/B double buffer
// (2 chunks each), #pragma unroll 1 so the scheduler cannot hoist the whole
// stream and spill (R1/R2 lesson). Verbatim R3-proven structure.
template <int COLS, int NCH>
__device__ __forceinline__ void seg3(const uint4* __restrict__ pz,
                                     const uint4* __restrict__ pr,
                                     const uint4* __restrict__ ph,
                                     const unsigned int* __restrict__ act,
                                     float& az, float& ar, float& a3)
{
    static_assert(NCH % 4 == 0, "NCH must be a multiple of 4");
    uint4 a_z0 = pz[0], a_z1 = pz[COLS];
    uint4 a_r0 = pr[0], a_r1 = pr[COLS];
    uint4 a_h0 = ph[0], a_h1 = ph[COLS];
    #pragma unroll 1
    for (int c = 0; c < NCH; c += 4) {
        const uint4* qz = pz + 2 * COLS;
        const uint4* qr = pr + 2 * COLS;
        const uint4* qh = ph + 2 * COLS;
        uint4 b_z0 = qz[0], b_z1 = qz[COLS];
        uint4 b_r0 = qr[0], b_r1 = qr[COLS];
        uint4 b_h0 = qh[0], b_h1 = qh[COLS];
        const uint4 v0 = *(const uint4*)(act);
        const uint4 v1 = *(const uint4*)(act + 4);
        dot4(az, a_z0, v0); dot4(ar, a_r0, v0); dot4(a3, a_h0, v0);
        dot4(az, a_z1, v1); dot4(ar, a_r1, v1); dot4(a3, a_h1, v1);
        pz += 4 * COLS; pr += 4 * COLS; ph += 4 * COLS;
        if (c + 4 < NCH) {
            a_z0 = pz[0]; a_z1 = pz[COLS];
            a_r0 = pr[0]; a_r1 = pr[COLS];
            a_h0 = ph[0]; a_h1 = ph[COLS];
        }
        const uint4 v2 = *(const uint4*)(act + 8);
        const uint4 v3 = *(const uint4*)(act + 12);
        act += 16;
        dot4(az, b_z0, v2); dot4(ar, b_r0, v2); dot4(a3, b_h0, v2);
        dot4(az, b_z1, v3); dot4(ar, b_r1, v3); dot4(a3, b_h1, v3);
    }
}

// 4-deep K-segment (NCH % 8 == 0): same discipline, A/B buffers of 4 chunks
// each -> 12 loads in flight per phase (2x R3's MLP). 24 named uint4 buffers
// = 96 VGPR; budget is 256 at 2 waves/SIMD (grid pins occupancy at 8 waves/CU
// anyway, so the extra registers are free).
template <int COLS, int NCH>
__device__ __forceinline__ void seg4(const uint4* __restrict__ pz,
                                     const uint4* __restrict__ pr,
                                     const uint4* __restrict__ ph,
                                     const unsigned int* __restrict__ act,
                                     float& az, float& ar, float& a3)
{
    static_assert(NCH % 8 == 0, "NCH must be a multiple of 8");
    uint4 a_z0 = pz[0], a_z1 = pz[COLS], a_z2 = pz[2 * COLS], a_z3 = pz[3 * COLS];
    uint4 a_r0 = pr[0], a_r1 = pr[COLS], a_r2 = pr[2 * COLS], a_r3 = pr[3 * COLS];
    uint4 a_h0 = ph[0], a_h1 = ph[COLS], a_h2 = ph[2 * COLS], a_h3 = ph[3 * COLS];
    #pragma unroll 1
    for (int c = 0; c < NCH; c += 8) {
        const uint4* qz = pz + 4 * COLS;
        const uint4* qr = pr + 4 * COLS;
        const uint4* qh = ph + 4 * COLS;
        uint4 b_z0 = qz[0], b_z1 = qz[COLS], b_z2 = qz[2 * COLS], b_z3 = qz[3 * COLS];
        uint4 b_r0 = qr[0], b_r1 = qr[COLS], b_r2 = qr[2 * COLS], b_r3 = qr[3 * COLS];
        uint4 b_h0 = qh[0], b_h1 = qh[COLS], b_h2 = qh[2 * COLS], b_h3 = qh[3 * COLS];
        {
            const uint4 v0 = *(const uint4*)(act);
            const uint4 v1 = *(const uint4*)(act + 4);
            const uint4 v2 = *(const uint4*)(act + 8);
            const uint4 v3 = *(const uint4*)(act + 12);
            dot4(az, a_z0, v0); dot4(ar, a_r0, v0); dot4(a3, a_h0, v0);
            dot4(az, a_z1, v1); dot4(ar, a_r1, v1); dot4(a3, a_h1, v1);
            dot4(az, a_z2, v2); dot4(ar, a_r2, v2); dot4(a3, a_h2, v2);
            dot4(az, a_z3, v3); dot4(ar, a_r3, v3); dot4(a3, a_h3, v3);
        }
        pz += 8 * COLS; pr += 8 * COLS; ph += 8 * COLS;
        if (c + 8 < NCH) {
            a_z0 = pz[0]; a_z1 = pz[COLS]; a_z2 = pz[2 * COLS]; a_z3 = pz[3 * COLS];
            a_r0 = pr[0]; a_r1 = pr[COLS]; a_r2 = pr[2 * COLS]; a_r3 = pr[3 * COLS];
            a_h0 = ph[0]; a_h1 = ph[COLS]; a_h2 = ph[2 * COLS]; a_h3 = ph[3 * COLS];
        }
        {
            const uint4 v4 = *(const uint4*)(act + 16);
            const uint4 v5 = *(const uint4*)(act + 20);
            const uint4 v6 = *(const uint4*)(act + 24);
            const uint4 v7 = *(const uint4*)(act + 28);
            act += 32;
            dot4(az, b_z0, v4); dot4(ar, b_r0, v4); dot4(a3, b_h0, v4);
            dot4(az, b_z1, v5); dot4(ar, b_r1, v5); dot4(a3, b_h1, v5);
            dot4(az, b_z2, v6); dot4(ar, b_r2, v6); dot4(a3, b_h2, v6);
            dot4(az, b_z3, v7); dot4(ar, b_r3, v7); dot4(a3, b_h3, v7);
        }
    }
}

// 256 WGs x 512 threads (8 waves/CU, grid-pinned), one batch row per WG.
// waves_per_eu pinned (2,2): grid=1 WG/CU makes >2 waves/SIMD unreachable, so
// give the allocator the full 256-VGPR budget and no squeeze incentive
// (R4/R5 lesson: the squeeze costs 640 MB of scratch).
// K-split: GRU1 by 2 (kh = tid&1), GRU2 by 4 (kq = tid&3); shfl_xor reduce.
// One barrier per timestep.
__global__ void
__attribute__((amdgpu_flat_work_group_size(512, 512)))
__attribute__((amdgpu_waves_per_eu(2, 2)))
gru_fused(const float* __restrict__ x,
          const float* __restrict__ b1, const float* __restrict__ b2,
          const float* __restrict__ w3, const float* __restrict__ b3,
          const float* __restrict__ w4, const float* __restrict__ b4,
          const float* __restrict__ w5, const float* __restrict__ b5,
          const unsigned int* __restrict__ wp,
          float* __restrict__ out)
{
    // fp16 activation pair buffers (uint = one half2), double-buffered.
    // act1: pairs [0..31] = x(t) (64 feats), pairs [32..159] = h1 (256 units)
    // act2: pairs [0..63] = h2 (128 units)
    __shared__ __align__(16) unsigned int act1[2][160];
    __shared__ __align__(16) unsigned int act2[2][64];
    __shared__ float h2fin[NU2];
    __shared__ float d3[64];
    __shared__ float d4[32];

    const int tid = threadIdx.x;
    const int row = blockIdx.x;
    const int j   = tid >> 1;       // GRU1 column (0..255)
    const int kh  = tid & 1;        // GRU1 K-half
    const int c2  = tid >> 2;       // GRU2 column (0..127)
    const int kq  = tid & 3;        // GRU2 K-quarter

    for (int i = tid; i < 2 * 160; i += 512) (&act1[0][0])[i] = 0u;
    for (int i = tid; i < 2 * 64;  i += 512) (&act2[0][0])[i] = 0u;

    // GRU1 biases (z,r folded; h kept split for reset_after), counted once via kh mask
    const float bm1  = (kh == 0) ? 1.0f : 0.0f;
    const float bz1  = (b1[j] + b1[768 + j]) * bm1;
    const float br1  = (b1[256 + j] + b1[1024 + j]) * bm1;
    const float bxh1 = b1[512 + j] * bm1;
    const float brh1 = b1[1280 + j] * bm1;
    // GRU2 biases, counted once via kq mask
    const float bm2  = (kq == 0) ? 1.0f : 0.0f;
    const float bz2  = (b2[c2] + b2[384 + c2]) * bm2;
    const float br2  = (b2[128 + c2] + b2[512 + c2]) * bm2;
    const float bxh2 = b2[256 + c2] * bm2;
    const float brh2 = b2[640 + c2] * bm2;

    const uint4* wp4 = (const uint4*)wp;
    const uint4* g1z = wp4 + G1Z_U4 + (kh * 20) * 256 + j;
    const uint4* g1r = wp4 + G1R_U4 + (kh * 20) * 256 + j;
    const uint4* g1h = wp4 + G1H_U4 + (kh * 20) * 256 + j;
    const uint4* g2z = wp4 + G2Z_U4 + (kq * 12) * 128 + c2;
    const uint4* g2r = wp4 + G2R_U4 + (kq * 12) * 128 + c2;
    const uint4* g2h = wp4 + G2H_U4 + (kq * 12) * 128 + c2;

    __syncthreads();   // zeros visible before x(0) pack overwrites x-part

    if (tid < FEAT) {
        float x0 = x[(size_t)row * TSEQ * FEAT + tid];
        float xb = __shfl_xor(x0, 1);
        if ((tid & 1) == 0) act1[0][tid >> 1] = pack2(x0, xb);
    }
    __syncthreads();

    float hp1 = 0.0f;   // h1 previous state, col j (redundant on the lane pair)
    float hp2 = 0.0f;   // h2 previous state, col c2 (redundant on the lane quad)

    for (int t = 0; t < TSEQ; ++t) {
        const int cur = t & 1, nb = cur ^ 1;

        // prefetch next x into registers (packed to LDS before the barrier)
        float xpre = 0.0f;
        if (t + 1 < TSEQ && tid < FEAT)
            xpre = x[(size_t)row * TSEQ * FEAT + (t + 1) * FEAT + tid];

        // ---------------- GRU1: reads act1[cur]; writes act1[nb] ----------------
        float az = bz1, ar = br1, aA = bxh1, aB = brh1;
        seg3<256, 4>(g1z, g1r, g1h, &act1[cur][kh * 16], az, ar, aA);
        seg4<256, 16>(g1z + 4 * 256, g1r + 4 * 256, g1h + 4 * 256,
                      &act1[cur][32 + kh * 64], az, ar, aB);
        az += __shfl_xor(az, 1);
        ar += __shfl_xor(ar, 1);
        aA += __shfl_xor(aA, 1);
        aB += __shfl_xor(aB, 1);
        {
            const float z  = sigmoid_f(az);
            const float rg = sigmoid_f(ar);
            const float hh = tanh_f(aA + rg * aB);
            const float hn = z * hp1 + (1.0f - z) * hh;
            hp1 = hn;
            const float hnb = __shfl_xor(hn, 2);   // partner column (2m+1) on lane 4m
            if ((tid & 3) == 0) act1[nb][32 + (tid >> 2)] = pack2(hn, hnb);
        }
        if (t + 1 < TSEQ && tid < FEAT) {
            float xb = __shfl_xor(xpre, 1);
            if ((tid & 1) == 0) act1[nb][tid >> 1] = pack2(xpre, xb);
        }
        __syncthreads();   // THE one barrier: act1[nb] (h1(t) + x(t+1)) visible

        // ---------------- GRU2: reads act1[nb] h-part, act2[cur]; writes act2[nb] ----------------
        float az2 = bz2, ar2 = br2, aA2 = bxh2, aB2 = brh2;
        seg4<128, 8>(g2z, g2r, g2h, &act1[nb][32 + kq * 32], az2, ar2, aA2);
        seg3<128, 4>(g2z + 8 * 128, g2r + 8 * 128, g2h + 8 * 128,
                     &act2[cur][kq * 16], az2, ar2, aB2);
        az2 += __shfl_xor(az2, 1); az2 += __shfl_xor(az2, 2);
        ar2 += __shfl_xor(ar2, 1); ar2 += __shfl_xor(ar2, 2);
        aA2 += __shfl_xor(aA2, 1); aA2 += __shfl_xor(aA2, 2);
        aB2 += __shfl_xor(aB2, 1); aB2 += __shfl_xor(aB2, 2);
        {
            const float z2v = sigmoid_f(az2);
            const float rg2 = sigmoid_f(ar2);
            const float hh2 = tanh_f(aA2 + rg2 * aB2);
            const float hn2 = z2v * hp2 + (1.0f - z2v) * hh2;
            hp2 = hn2;
            const float hnb2 = __shfl_xor(hn2, 4); // partner column (2m+1) on lane 8m
            if ((tid & 7) == 0) act2[nb][tid >> 3] = pack2(hn2, hnb2);
        }
        // no second barrier: next step's barrier covers act2[nb] visibility;
        // all WAR hazards are buffer-separated (same discipline as proven kernel)
    }

    if ((tid & 3) == 0) h2fin[c2] = hp2;   // final h2 state, fp32
    __syncthreads();

    // ---------------- dense head: h2 -> 64 -> 32 -> 24 ----------------
    if (tid < 64) {
        float a = b3[tid];
        #pragma unroll 4
        for (int u = 0; u < NU2; ++u) a += h2fin[u] * w3[u * 64 + tid];
        d3[tid] = a;
    }
    __syncthreads();
    if (tid < 32) {
        float a = b4[tid];
        #pragma unroll 4
        for (int u = 0; u < 64; ++u) a += d3[u] * w4[u * 32 + tid];
        d4[tid] = a;
    }
    __syncthreads();
    if (tid < 24) {
        float a = b5[tid];
        #pragma unroll 4
        for (int u = 0; u < 32; ++u) a += d4[u] * w5[u * 24 + tid];
        out[(size_t)row * 24 + tid] = a;
    }
}

extern "C" void kernel_launch(void* const* d_in, const int* in_sizes, int n_in,
                              void* d_out, int out_size, void* d_ws, size_t ws_size,
                              hipStream_t stream) {
    (void)in_sizes; (void)n_in; (void)ws_size; (void)out_size;
    const float* x  = (const float*)d_in[0];
    const float* k1 = (const float*)d_in[1];
    const float* r1 = (const float*)d_in[2];
    const float* b1 = (const float*)d_in[3];
    const float* k2 = (const float*)d_in[4];
    const float* r2 = (const float*)d_in[5];
    const float* b2 = (const float*)d_in[6];
    const float* w3 = (const float*)d_in[7];
    const float* b3 = (const float*)d_in[8];
    const float* w4 = (const float*)d_in[9];
    const float* b4 = (const float*)d_in[10];
    const float* w5 = (const float*)d_in[11];
    const float* b5 = (const float*)d_in[12];
    float* out = (float*)d_out;

    hipLaunchKernelGGL(pack_weights, dim3((TOTAL_H2 + 255) / 256), dim3(256), 0, stream,
                       k1, r1, k2, r2, (__half2*)d_ws);
    hipLaunchKernelGGL(gru_fused, dim3(BATCH), dim3(512), 0, stream,
                       x, b1, b2, w3, b3, w4, b4, w5, b5,
                       (const unsigned int*)d_ws, out);
}

// Round 8
// 4739.371 us; speedup vs baseline: 2.4033x; 2.3813x over previous
//
#include <hip/hip_runtime.h>
#include <hip/hip_fp16.h>
#include <math.h>

// Problem constants
#define BATCH 256
#define TSEQ  512
#define FEAT  64
#define NU1   256
#define NU2   128

// half2-element offsets of packed fp16 weight planes inside d_ws.
// Quad-pair planes, K-split-contiguous chunk order (one chunk = 4 half2 row-pairs):
// GRU1 plane (per gate): [2 kh][20 chunks][256 cols][4]
//   chunks 0..3  = x rows (kh half: feats kh*32..kh*32+31  = act1 pairs kh*16+0..15)
//   chunks 4..19 = h1 rows (kh half: units kh*128..kh*128+127 = act1 pairs 32+kh*64+0..63)
// GRU2 plane (per gate): [4 kq][12 chunks][128 cols][4]
//   chunks 0..7  = h1 rows (kq quarter: units kq*64..kq*64+63 = act1 pairs 32+kq*32+0..31)
//   chunks 8..11 = h2 rows (kq quarter: units kq*32..kq*32+31 = act2 pairs kq*16+0..15)
#define G1Z_OFF 0
#define G1R_OFF 40960
#define G1H_OFF 81920
#define G2Z_OFF 122880
#define G2R_OFF 147456
#define G2H_OFF 172032
#define TOTAL_H2 196608   // 786,432 bytes of d_ws

// uint4-unit plane offsets (half2 offset / 4)
#define G1Z_U4 0
#define G1R_U4 10240
#define G1H_U4 20480
#define G2Z_U4 30720
#define G2R_U4 36864
#define G2H_U4 43008

// dynamic-LDS park size: GRU2 h2-part (6144 uint4) + GRU1 x-part (3072 uint4)
#define LDS_PARK_BYTES (9216 * 16)   // 147,456 B

typedef _Float16 h2f __attribute__((ext_vector_type(2)));

__device__ __forceinline__ float sigmoid_f(float v) {
    return 1.0f / (1.0f + __expf(-v));
}
__device__ __forceinline__ float tanh_f(float v) {
    float c = fminf(fmaxf(v, -15.0f), 15.0f);
    float e = __expf(2.0f * c);
    return (e - 1.0f) / (e + 1.0f);
}

__device__ __forceinline__ h2f bch2(unsigned int u) {
    return __builtin_bit_cast(h2f, u);
}
__device__ __forceinline__ unsigned int pack2(float a, float b) {
    h2f v;
    v.x = (_Float16)a;
    v.y = (_Float16)b;
    return __builtin_bit_cast(unsigned int, v);
}

// acc += dot of 4 half2 pairs (8 fp16 weights x 8 fp16 activations), fp32 accum
__device__ __forceinline__ void dot4(float& acc, uint4 w, uint4 a) {
    acc = __builtin_amdgcn_fdot2(bch2(w.x), bch2(a.x), acc, false);
    acc = __builtin_amdgcn_fdot2(bch2(w.y), bch2(a.y), acc, false);
    acc = __builtin_amdgcn_fdot2(bch2(w.z), bch2(a.z), acc, false);
    acc = __builtin_amdgcn_fdot2(bch2(w.w), bch2(a.w), acc, false);
}

// ---------------- weight packing (fp32 -> fp16 quad-pair planes) ----------------
// R3-proven layout: GRU1 [2 kh][20 chunks], GRU2 [4 kq][12 chunks]. UNCHANGED.
__global__ void pack_weights(const float* __restrict__ k1, const float* __restrict__ r1,
                             const float* __restrict__ k2, const float* __restrict__ r2,
                             __half2* __restrict__ ws)
{
    int idx = blockIdx.x * 256 + threadIdx.x;
    if (idx >= TOTAL_H2) return;
    float a, b;
    if (idx < G2Z_OFF) {
        // GRU1 planes: 3 x [2 kh][20 chunks][256 cols][4]
        int plane = idx / 40960;       // 0=z 1=r 2=h
        int rem   = idx % 40960;       // = cc*1024 + col*4 + q
        int cc    = rem >> 10;         // 0..39
        int col   = (rem >> 2) & 255;
        int q     = rem & 3;
        int kh    = cc / 20;
        int c     = cc - kh * 20;
        int g     = plane * 256 + col; // gate-column in [0,768)
        int pair  = (c < 4) ? ((kh * 4 + c) * 4 + q)
                            : (32 + (kh * 16 + (c - 4)) * 4 + q);
        int row0  = pair * 2;
        if (row0 < 64) { a = k1[row0 * 768 + g];        b = k1[(row0 + 1) * 768 + g]; }
        else           { a = r1[(row0 - 64) * 768 + g]; b = r1[(row0 - 63) * 768 + g]; }
    } else {
        // GRU2 planes: 3 x [4 kq][12 chunks][128 cols][4]
        int idx2  = idx - G2Z_OFF;
        int plane = idx2 / 24576;
        int rem   = idx2 % 24576;      // = cc*512 + col*4 + q
        int cc    = rem >> 9;          // 0..47
        int col   = (rem >> 2) & 127;
        int q     = rem & 3;
        int kq    = cc / 12;
        int c     = cc - kq * 12;
        int g     = plane * 128 + col; // gate-column in [0,384)
        int pair  = (c < 8) ? ((kq * 8 + c) * 4 + q)
                            : (128 + (kq * 4 + (c - 8)) * 4 + q);
        int row0  = pair * 2;
        if (row0 < 256) { a = k2[row0 * 384 + g];         b = k2[(row0 + 1) * 384 + g]; }
        else            { a = r2[(row0 - 256) * 384 + g]; b = r2[(row0 - 255) * 384 + g]; }
    }
    __half2 h;
    h.x = __float2half_rn(a);
    h.y = __float2half_rn(b);
    ws[idx] = h;
}

// 2-deep K-segment (NCH % 4 == 0): 3 gate streams, NAMED A/B double buffer
// (2 chunks each), #pragma unroll 1 so the scheduler cannot hoist the whole
// stream and spill (R1/R2 lesson). Verbatim R3-proven structure. Works for
// both global and LDS weight pointers (forceinline -> per-callsite addrspace
// inference; LDS callers emit ds_read_b128).
template <int COLS, int NCH>
__device__ __forceinline__ void seg3(const uint4* __restrict__ pz,
                                     const uint4* __restrict__ pr,
                                     const uint4* __restrict__ ph,
                                     const unsigned int* __restrict__ act,
                                     float& az, float& ar, float& a3)
{
    static_assert(NCH % 4 == 0, "NCH must be a multiple of 4");
    uint4 a_z0 = pz[0], a_z1 = pz[COLS];
    uint4 a_r0 = pr[0], a_r1 = pr[COLS];
    uint4 a_h0 = ph[0], a_h1 = ph[COLS];
    #pragma unroll 1
    for (int c = 0; c < NCH; c += 4) {
        const uint4* qz = pz + 2 * COLS;
        const uint4* qr = pr + 2 * COLS;
        const uint4* qh = ph + 2 * COLS;
        uint4 b_z0 = qz[0], b_z1 = qz[COLS];
        uint4 b_r0 = qr[0], b_r1 = qr[COLS];
        uint4 b_h0 = qh[0], b_h1 = qh[COLS];
        const uint4 v0 = *(const uint4*)(act);
        const uint4 v1 = *(const uint4*)(act + 4);
        dot4(az, a_z0, v0); dot4(ar, a_r0, v0); dot4(a3, a_h0, v0);
        dot4(az, a_z1, v1); dot4(ar, a_r1, v1); dot4(a3, a_h1, v1);
        pz += 4 * COLS; pr += 4 * COLS; ph += 4 * COLS;
        if (c + 4 < NCH) {
            a_z0 = pz[0]; a_z1 = pz[COLS];
            a_r0 = pr[0]; a_r1 = pr[COLS];
            a_h0 = ph[0]; a_h1 = ph[COLS];
        }
        const uint4 v2 = *(const uint4*)(act + 8);
        const uint4 v3 = *(const uint4*)(act + 12);
        act += 16;
        dot4(az, b_z0, v2); dot4(ar, b_r0, v2); dot4(a3, b_h0, v2);
        dot4(az, b_z1, v3); dot4(ar, b_r1, v3); dot4(a3, b_h1, v3);
    }
}

// 2-chunk straight-line segment (used for split x-part: LDS half + global half)
template <int COLS>
__device__ __forceinline__ void seg_pair(const uint4* __restrict__ pz,
                                         const uint4* __restrict__ pr,
                                         const uint4* __restrict__ ph,
                                         const unsigned int* __restrict__ act,
                                         float& az, float& ar, float& a3)
{
    uint4 z0 = pz[0], z1 = pz[COLS];
    uint4 r0 = pr[0], r1 = pr[COLS];
    uint4 h0 = ph[0], h1 = ph[COLS];
    const uint4 v0 = *(const uint4*)(act);
    const uint4 v1 = *(const uint4*)(act + 4);
    dot4(az, z0, v0); dot4(ar, r0, v0); dot4(a3, h0, v0);
    dot4(az, z1, v1); dot4(ar, r1, v1); dot4(a3, h1, v1);
}

// 256 WGs x 512 threads (8 waves/CU, grid-pinned), one batch row per WG.
// Exact R3 config (proven: VGPR=128, no meaningful spill, 5191 us).
// NEW vs R3: 147 KB of weight planes parked persistently in DYNAMIC LDS
// (R7 lesson: static __shared__ is capped at 64 KB -- must go through
// extern __shared__ + hipFuncAttributeMaxDynamicSharedMemorySize).
// Written once, read 512x; global port stream drops 786 -> 639 KB/step.
// K-split: GRU1 by 2 (kh = tid&1), GRU2 by 4 (kq = tid&3); shfl_xor reduce.
// One barrier per timestep.
__global__ __launch_bounds__(512, 2)
void gru_fused(const float* __restrict__ x,
               const float* __restrict__ b1, const float* __restrict__ b2,
               const float* __restrict__ w3, const float* __restrict__ b3,
               const float* __restrict__ w4, const float* __restrict__ b4,
               const float* __restrict__ w5, const float* __restrict__ b5,
               const unsigned int* __restrict__ wp,
               float* __restrict__ out)
{
    // Parked weights: dynamic LDS, 147,456 B.
    //   lwdyn[0    .. 6143] = GRU2 h2-part: [gate][kq][c<4][col128]  (98,304 B)
    //   lwdyn[6144 .. 9215] = GRU1 x-part:  [gate][kh][c<2][col256]  (49,152 B)
    extern __shared__ __align__(16) uint4 lwdyn[];
    uint4* lw2 = lwdyn;
    uint4* lw1 = lwdyn + 6144;
    // fp16 activation pair buffers (uint = one half2), double-buffered. (static, ~2.7 KB)
    __shared__ __align__(16) unsigned int act1[2][160];   // [0..31]=x(t), [32..159]=h1
    __shared__ __align__(16) unsigned int act2[2][64];    // h2
    __shared__ float h2fin[NU2];
    __shared__ float d3[64];
    __shared__ float d4[32];

    const int tid = threadIdx.x;
    const int row = blockIdx.x;
    const int j   = tid >> 1;       // GRU1 column (0..255)
    const int kh  = tid & 1;        // GRU1 K-half
    const int c2  = tid >> 2;       // GRU2 column (0..127)
    const int kq  = tid & 3;        // GRU2 K-quarter

    const uint4* wp4 = (const uint4*)wp;

    // ---- park weights into LDS (once; bit-exact copy of packed planes) ----
    // lw2[i]: i = g*2048 + kq*512 + c*128 + col  <-  GRU2 plane g, chunk kq*12+8+c
    for (int i = tid; i < 6144; i += 512) {
        int col = i & 127, c = (i >> 7) & 3, kk = (i >> 9) & 3, g = i >> 11;
        lw2[i] = wp4[G2Z_U4 + g * 6144 + (kk * 12 + 8 + c) * 128 + col];
    }
    // lw1[i]: i = g*1024 + kh*512 + c*256 + col  <-  GRU1 plane g, chunk kh*20+c
    for (int i = tid; i < 3072; i += 512) {
        int col = i & 255, c = (i >> 8) & 1, hh = (i >> 9) & 1, g = i >> 10;
        lw1[i] = wp4[G1Z_U4 + g * 10240 + (hh * 20 + c) * 256 + col];
    }

    for (int i = tid; i < 2 * 160; i += 512) (&act1[0][0])[i] = 0u;
    for (int i = tid; i < 2 * 64;  i += 512) (&act2[0][0])[i] = 0u;

    // GRU1 biases (z,r folded; h kept split for reset_after), counted once via kh mask
    const float bm1  = (kh == 0) ? 1.0f : 0.0f;
    const float bz1  = (b1[j] + b1[768 + j]) * bm1;
    const float br1  = (b1[256 + j] + b1[1024 + j]) * bm1;
    const float bxh1 = b1[512 + j] * bm1;
    const float brh1 = b1[1280 + j] * bm1;
    // GRU2 biases, counted once via kq mask
    const float bm2  = (kq == 0) ? 1.0f : 0.0f;
    const float bz2  = (b2[c2] + b2[384 + c2]) * bm2;
    const float br2  = (b2[128 + c2] + b2[512 + c2]) * bm2;
    const float bxh2 = b2[256 + c2] * bm2;
    const float brh2 = b2[640 + c2] * bm2;

    // global weight bases (per thread column)
    const uint4* g1z = wp4 + G1Z_U4 + (kh * 20) * 256 + j;
    const uint4* g1r = wp4 + G1R_U4 + (kh * 20) * 256 + j;
    const uint4* g1h = wp4 + G1H_U4 + (kh * 20) * 256 + j;
    const uint4* g2z = wp4 + G2Z_U4 + (kq * 12) * 128 + c2;
    const uint4* g2r = wp4 + G2R_U4 + (kq * 12) * 128 + c2;
    const uint4* g2h = wp4 + G2H_U4 + (kq * 12) * 128 + c2;
    // LDS weight bases (gate stride: lw1=1024, lw2=2048 uint4)
    const uint4* l1z = lw1 + kh * 512 + j;
    const uint4* l2z = lw2 + kq * 512 + c2;

    __syncthreads();   // parked weights + zeros visible

    if (tid < FEAT) {
        float x0 = x[(size_t)row * TSEQ * FEAT + tid];
        float xb = __shfl_xor(x0, 1);
        if ((tid & 1) == 0) act1[0][tid >> 1] = pack2(x0, xb);
    }
    __syncthreads();

    float hp1 = 0.0f;   // h1 previous state, col j (redundant on the lane pair)
    float hp2 = 0.0f;   // h2 previous state, col c2 (redundant on the lane quad)

    for (int t = 0; t < TSEQ; ++t) {
        const int cur = t & 1, nb = cur ^ 1;

        // prefetch next x into registers (packed to LDS before the barrier)
        float xpre = 0.0f;
        if (t + 1 < TSEQ && tid < FEAT)
            xpre = x[(size_t)row * TSEQ * FEAT + (t + 1) * FEAT + tid];

        // ---------------- GRU1: reads act1[cur]; writes act1[nb] ----------------
        float az = bz1, ar = br1, aA = bxh1, aB = brh1;
        // x-part: chunks 0-1 from LDS, chunks 2-3 from global
        seg_pair<256>(l1z, l1z + 1024, l1z + 2048,
                      &act1[cur][kh * 16], az, ar, aA);
        seg_pair<256>(g1z + 2 * 256, g1r + 2 * 256, g1h + 2 * 256,
                      &act1[cur][kh * 16 + 8], az, ar, aA);
        // h-part: 16 chunks from global (unchanged R3 path)
        seg3<256, 16>(g1z + 4 * 256, g1r + 4 * 256, g1h + 4 * 256,
                      &act1[cur][32 + kh * 64], az, ar, aB);
        az += __shfl_xor(az, 1);
        ar += __shfl_xor(ar, 1);
        aA += __shfl_xor(aA, 1);
        aB += __shfl_xor(aB, 1);
        {
            const float z  = sigmoid_f(az);
            const float rg = sigmoid_f(ar);
            const float hh = tanh_f(aA + rg * aB);
            const float hn = z * hp1 + (1.0f - z) * hh;
            hp1 = hn;
            const float hnb = __shfl_xor(hn, 2);   // partner column (2m+1) on lane 4m
            if ((tid & 3) == 0) act1[nb][32 + (tid >> 2)] = pack2(hn, hnb);
        }
        if (t + 1 < TSEQ && tid < FEAT) {
            float xb = __shfl_xor(xpre, 1);
            if ((tid & 1) == 0) act1[nb][tid >> 1] = pack2(xpre, xb);
        }
        __syncthreads();   // THE one barrier: act1[nb] (h1(t) + x(t+1)) visible

        // ---------------- GRU2: reads act1[nb] h-part, act2[cur]; writes act2[nb] ----------------
        float az2 = bz2, ar2 = br2, aA2 = bxh2, aB2 = brh2;
        // h1-part: 8 chunks from global (unchanged R3 path)
        seg3<128, 8>(g2z, g2r, g2h, &act1[nb][32 + kq * 32], az2, ar2, aA2);
        // h2-part: 4 chunks from LDS
        seg3<128, 4>(l2z, l2z + 2048, l2z + 4096,
                     &act2[cur][kq * 16], az2, ar2, aB2);
        az2 += __shfl_xor(az2, 1); az2 += __shfl_xor(az2, 2);
        ar2 += __shfl_xor(ar2, 1); ar2 += __shfl_xor(ar2, 2);
        aA2 += __shfl_xor(aA2, 1); aA2 += __shfl_xor(aA2, 2);
        aB2 += __shfl_xor(aB2, 1); aB2 += __shfl_xor(aB2, 2);
        {
            const float z2v = sigmoid_f(az2);
            const float rg2 = sigmoid_f(ar2);
            const float hh2 = tanh_f(aA2 + rg2 * aB2);
            const float hn2 = z2v * hp2 + (1.0f - z2v) * hh2;
            hp2 = hn2;
            const float hnb2 = __shfl_xor(hn2, 4); // partner column (2m+1) on lane 8m
            if ((tid & 7) == 0) act2[nb][tid >> 3] = pack2(hn2, hnb2);
        }
        // no second barrier: next step's barrier covers act2[nb] visibility;
        // all WAR hazards are buffer-separated (same discipline as proven kernel)
    }

    if ((tid & 3) == 0) h2fin[c2] = hp2;   // final h2 state, fp32
    __syncthreads();

    // ---------------- dense head: h2 -> 64 -> 32 -> 24 ----------------
    if (tid < 64) {
        float a = b3[tid];
        #pragma unroll 4
        for (int u = 0; u < NU2; ++u) a += h2fin[u] * w3[u * 64 + tid];
        d3[tid] = a;
    }
    __syncthreads();
    if (tid < 32) {
        float a = b4[tid];
        #pragma unroll 4
        for (int u = 0; u < 64; ++u) a += d3[u] * w4[u * 32 + tid];
        d4[tid] = a;
    }
    __syncthreads();
    if (tid < 24) {
        float a = b5[tid];
        #pragma unroll 4
        for (int u = 0; u < 32; ++u) a += d4[u] * w5[u * 24 + tid];
        out[(size_t)row * 24 + tid] = a;
    }
}

extern "C" void kernel_launch(void* const* d_in, const int* in_sizes, int n_in,
                              void* d_out, int out_size, void* d_ws, size_t ws_size,
                              hipStream_t stream) {
    (void)in_sizes; (void)n_in; (void)ws_size; (void)out_size;
    const float* x  = (const float*)d_in[0];
    const float* k1 = (const float*)d_in[1];
    const float* r1 = (const float*)d_in[2];
    const float* b1 = (const float*)d_in[3];
    const float* k2 = (const float*)d_in[4];
    const float* r2 = (const float*)d_in[5];
    const float* b2 = (const float*)d_in[6];
    const float* w3 = (const float*)d_in[7];
    const float* b3 = (const float*)d_in[8];
    const float* w4 = (const float*)d_in[9];
    const float* b4 = (const float*)d_in[10];
    const float* w5 = (const float*)d_in[11];
    const float* b5 = (const float*)d_in[12];
    float* out = (float*)d_out;

    // Opt in to >64 KB dynamic LDS (host-side, executes at capture time; only
    // needs to succeed once -- ignore the return on repeat calls).
    static bool lds_attr_set = false;
    if (!lds_attr_set) {
        (void)hipFuncSetAttribute((const void*)gru_fused,
                                  hipFuncAttributeMaxDynamicSharedMemorySize,
                                  LDS_PARK_BYTES);
        lds_attr_set = true;
    }

    hipLaunchKernelGGL(pack_weights, dim3((TOTAL_H2 + 255) / 256), dim3(256), 0, stream,
                       k1, r1, k2, r2, (__half2*)d_ws);
    hipLaunchKernelGGL(gru_fused, dim3(BATCH), dim3(512), LDS_PARK_BYTES, stream,
                       x, b1, b2, w3, b3, w4, b4, w5, b5,
                       (const unsigned int*)d_ws, out);
}

// Round 9
// 4718.412 us; speedup vs baseline: 2.4140x; 1.0044x over previous
//
#include <hip/hip_runtime.h>
#include <hip/hip_fp16.h>
#include <math.h>

// Problem constants
#define BATCH 256
#define TSEQ  512
#define FEAT  64
#define NU1   256
#define NU2   128

// half2-element offsets of packed fp16 weight planes inside d_ws.
// Quad-pair planes, K-split-contiguous chunk order (one chunk = 4 half2 row-pairs):
// GRU1 plane (per gate): [2 kh][20 chunks][256 cols][4]
//   chunks 0..3  = x rows (kh half: feats kh*32..kh*32+31  = act1 pairs kh*16+0..15)
//   chunks 4..19 = h1 rows (kh half: units kh*128..kh*128+127 = act1 pairs 32+kh*64+0..63)
// GRU2 plane (per gate): [4 kq][12 chunks][128 cols][4]
//   chunks 0..7  = h1 rows (kq quarter: units kq*64..kq*64+63 = act1 pairs 32+kq*32+0..31)
//   chunks 8..11 = h2 rows (kq quarter: units kq*32..kq*32+31 = act2 pairs kq*16+0..15)
#define G1Z_OFF 0
#define G1R_OFF 40960
#define G1H_OFF 81920
#define G2Z_OFF 122880
#define G2R_OFF 147456
#define G2H_OFF 172032
#define TOTAL_H2 196608   // 786,432 bytes of d_ws

// uint4-unit plane offsets (half2 offset / 4)
#define G1Z_U4 0
#define G1R_U4 10240
#define G1H_U4 20480
#define G2Z_U4 30720
#define G2R_U4 36864
#define G2H_U4 43008

// dynamic-LDS park size: GRU2 h2-part (6144 uint4) + GRU1 x-part (3072 uint4)
#define LDS_PARK_BYTES (9216 * 16)   // 147,456 B

typedef _Float16 h2f __attribute__((ext_vector_type(2)));

__device__ __forceinline__ float sigmoid_f(float v) {
    return 1.0f / (1.0f + __expf(-v));
}
__device__ __forceinline__ float tanh_f(float v) {
    float c = fminf(fmaxf(v, -15.0f), 15.0f);
    float e = __expf(2.0f * c);
    return (e - 1.0f) / (e + 1.0f);
}

__device__ __forceinline__ h2f bch2(unsigned int u) {
    return __builtin_bit_cast(h2f, u);
}
__device__ __forceinline__ unsigned int pack2(float a, float b) {
    h2f v;
    v.x = (_Float16)a;
    v.y = (_Float16)b;
    return __builtin_bit_cast(unsigned int, v);
}

// acc += dot of 4 half2 pairs (8 fp16 weights x 8 fp16 activations), fp32 accum
__device__ __forceinline__ void dot4(float& acc, uint4 w, uint4 a) {
    acc = __builtin_amdgcn_fdot2(bch2(w.x), bch2(a.x), acc, false);
    acc = __builtin_amdgcn_fdot2(bch2(w.y), bch2(a.y), acc, false);
    acc = __builtin_amdgcn_fdot2(bch2(w.z), bch2(a.z), acc, false);
    acc = __builtin_amdgcn_fdot2(bch2(w.w), bch2(a.w), acc, false);
}

// ---------------- weight packing (fp32 -> fp16 quad-pair planes) ----------------
// R3-proven layout: GRU1 [2 kh][20 chunks], GRU2 [4 kq][12 chunks]. UNCHANGED.
__global__ void pack_weights(const float* __restrict__ k1, const float* __restrict__ r1,
                             const float* __restrict__ k2, const float* __restrict__ r2,
                             __half2* __restrict__ ws)
{
    int idx = blockIdx.x * 256 + threadIdx.x;
    if (idx >= TOTAL_H2) return;
    float a, b;
    if (idx < G2Z_OFF) {
        // GRU1 planes: 3 x [2 kh][20 chunks][256 cols][4]
        int plane = idx / 40960;       // 0=z 1=r 2=h
        int rem   = idx % 40960;       // = cc*1024 + col*4 + q
        int cc    = rem >> 10;         // 0..39
        int col   = (rem >> 2) & 255;
        int q     = rem & 3;
        int kh    = cc / 20;
        int c     = cc - kh * 20;
        int g     = plane * 256 + col; // gate-column in [0,768)
        int pair  = (c < 4) ? ((kh * 4 + c) * 4 + q)
                            : (32 + (kh * 16 + (c - 4)) * 4 + q);
        int row0  = pair * 2;
        if (row0 < 64) { a = k1[row0 * 768 + g];        b = k1[(row0 + 1) * 768 + g]; }
        else           { a = r1[(row0 - 64) * 768 + g]; b = r1[(row0 - 63) * 768 + g]; }
    } else {
        // GRU2 planes: 3 x [4 kq][12 chunks][128 cols][4]
        int idx2  = idx - G2Z_OFF;
        int plane = idx2 / 24576;
        int rem   = idx2 % 24576;      // = cc*512 + col*4 + q
        int cc    = rem >> 9;          // 0..47
        int col   = (rem >> 2) & 127;
        int q     = rem & 3;
        int kq    = cc / 12;
        int c     = cc - kq * 12;
        int g     = plane * 128 + col; // gate-column in [0,384)
        int pair  = (c < 8) ? ((kq * 8 + c) * 4 + q)
                            : (128 + (kq * 4 + (c - 8)) * 4 + q);
        int row0  = pair * 2;
        if (row0 < 256) { a = k2[row0 * 384 + g];         b = k2[(row0 + 1) * 384 + g]; }
        else            { a = r2[(row0 - 256) * 384 + g]; b = r2[(row0 - 255) * 384 + g]; }
    }
    __half2 h;
    h.x = __float2half_rn(a);
    h.y = __float2half_rn(b);
    ws[idx] = h;
}

// 2-deep K-segment (NCH % 4 == 0): 3 gate streams, NAMED A/B double buffer
// (2 chunks each), #pragma unroll 1 so the scheduler cannot hoist the whole
// stream and spill (R1/R2 lesson). Verbatim R3-proven structure. Works for
// both global and LDS weight pointers (forceinline -> per-callsite addrspace
// inference; LDS callers emit ds_read_b128). COLS = chunk stride in uint4.
template <int COLS, int NCH>
__device__ __forceinline__ void seg3(const uint4* __restrict__ pz,
                                     const uint4* __restrict__ pr,
                                     const uint4* __restrict__ ph,
                                     const unsigned int* __restrict__ act,
                                     float& az, float& ar, float& a3)
{
    static_assert(NCH % 4 == 0, "NCH must be a multiple of 4");
    uint4 a_z0 = pz[0], a_z1 = pz[COLS];
    uint4 a_r0 = pr[0], a_r1 = pr[COLS];
    uint4 a_h0 = ph[0], a_h1 = ph[COLS];
    #pragma unroll 1
    for (int c = 0; c < NCH; c += 4) {
        const uint4* qz = pz + 2 * COLS;
        const uint4* qr = pr + 2 * COLS;
        const uint4* qh = ph + 2 * COLS;
        uint4 b_z0 = qz[0], b_z1 = qz[COLS];
        uint4 b_r0 = qr[0], b_r1 = qr[COLS];
        uint4 b_h0 = qh[0], b_h1 = qh[COLS];
        const uint4 v0 = *(const uint4*)(act);
        const uint4 v1 = *(const uint4*)(act + 4);
        dot4(az, a_z0, v0); dot4(ar, a_r0, v0); dot4(a3, a_h0, v0);
        dot4(az, a_z1, v1); dot4(ar, a_r1, v1); dot4(a3, a_h1, v1);
        pz += 4 * COLS; pr += 4 * COLS; ph += 4 * COLS;
        if (c + 4 < NCH) {
            a_z0 = pz[0]; a_z1 = pz[COLS];
            a_r0 = pr[0]; a_r1 = pr[COLS];
            a_h0 = ph[0]; a_h1 = ph[COLS];
        }
        const uint4 v2 = *(const uint4*)(act + 8);
        const uint4 v3 = *(const uint4*)(act + 12);
        act += 16;
        dot4(az, b_z0, v2); dot4(ar, b_r0, v2); dot4(a3, b_h0, v2);
        dot4(az, b_z1, v3); dot4(ar, b_r1, v3); dot4(a3, b_h1, v3);
    }
}

// 2-chunk straight-line segment (used for split x-part: LDS half + global half)
template <int COLS>
__device__ __forceinline__ void seg_pair(const uint4* __restrict__ pz,
                                         const uint4* __restrict__ pr,
                                         const uint4* __restrict__ ph,
                                         const unsigned int* __restrict__ act,
                                         float& az, float& ar, float& a3)
{
    uint4 z0 = pz[0], z1 = pz[COLS];
    uint4 r0 = pr[0], r1 = pr[COLS];
    uint4 h0 = ph[0], h1 = ph[COLS];
    const uint4 v0 = *(const uint4*)(act);
    const uint4 v1 = *(const uint4*)(act + 4);
    dot4(az, z0, v0); dot4(ar, r0, v0); dot4(a3, h0, v0);
    dot4(az, z1, v1); dot4(ar, r1, v1); dot4(a3, h1, v1);
}

// 256 WGs x 512 threads (8 waves/CU, grid-pinned), one batch row per WG.
// R8 base (147 KB dynamic-LDS weight park, proven 4739 us) + two bank-conflict
// fixes (R8 PMC: SQ_LDS_BANK_CONFLICT 2.77e8, 4-way on parked reads + GRU2 act):
//  (a) LANE-LINEAR park layout lw[(c*3+g)*512 + tid]: a wave's 64 lanes read 64
//      consecutive uint4s -> each 16-lane phase covers all 32 banks exactly
//      twice (2-way = free, m136). Was kq*512+c2 -> 4 lanes per bank quad.
//  (b) skewed replica act1s of the h1 activations for GRU2's reads: kq blocks
//      at stride 40 uints -> block starts at banks {0,8,16,24} (was all 0).
// K-split: GRU1 by 2 (kh = tid&1), GRU2 by 4 (kq = tid&3); shfl_xor reduce.
// One barrier per timestep.
__global__ __launch_bounds__(512, 2)
void gru_fused(const float* __restrict__ x,
               const float* __restrict__ b1, const float* __restrict__ b2,
               const float* __restrict__ w3, const float* __restrict__ b3,
               const float* __restrict__ w4, const float* __restrict__ b4,
               const float* __restrict__ w5, const float* __restrict__ b5,
               const unsigned int* __restrict__ wp,
               float* __restrict__ out)
{
    // Parked weights: dynamic LDS, 147,456 B, lane-linear layout.
    //   lw2[(c*3+g)*512 + tid], c=0..3: GRU2 h2-part chunk kq*12+8+c, col c2 (98,304 B)
    //   lw1[(c*3+g)*512 + tid], c=0..1: GRU1 x-part  chunk kh*20+c,   col j  (49,152 B)
    extern __shared__ __align__(16) uint4 lwdyn[];
    uint4* lw2 = lwdyn;
    uint4* lw1 = lwdyn + 6144;
    // fp16 activation pair buffers (uint = one half2), double-buffered. (static)
    __shared__ __align__(16) unsigned int act1[2][160];   // [0..31]=x(t), [32..159]=h1
    __shared__ __align__(16) unsigned int act2[2][64];    // h2
    __shared__ __align__(16) unsigned int act1s[2][160];  // skewed h1 replica: kq block at kq*40
    __shared__ float h2fin[NU2];
    __shared__ float d3[64];
    __shared__ float d4[32];

    const int tid = threadIdx.x;
    const int row = blockIdx.x;
    const int j   = tid >> 1;       // GRU1 column (0..255)
    const int kh  = tid & 1;        // GRU1 K-half
    const int c2  = tid >> 2;       // GRU2 column (0..127)
    const int kq  = tid & 3;        // GRU2 K-quarter

    const uint4* wp4 = (const uint4*)wp;

    // ---- park weights into LDS (once; lane-linear layout) ----
    // lw2[i]: i = (c*3+g)*512 + tid  <-  GRU2 plane g, chunk kq*12+8+c, col c2
    for (int i = tid; i < 6144; i += 512) {
        int cg = i >> 9;               // tid < 512 so i>>9 == block index
        int c  = cg / 3, g = cg - 3 * c;
        lw2[i] = wp4[G2Z_U4 + g * 6144 + (kq * 12 + 8 + c) * 128 + c2];
    }
    // lw1[i]: i = (c*3+g)*512 + tid  <-  GRU1 plane g, chunk kh*20+c, col j
    for (int i = tid; i < 3072; i += 512) {
        int cg = i >> 9;
        int c  = cg / 3, g = cg - 3 * c;
        lw1[i] = wp4[G1Z_U4 + g * 10240 + (kh * 20 + c) * 256 + j];
    }

    for (int i = tid; i < 2 * 160; i += 512) (&act1[0][0])[i]  = 0u;
    for (int i = tid; i < 2 * 64;  i += 512) (&act2[0][0])[i]  = 0u;
    for (int i = tid; i < 2 * 160; i += 512) (&act1s[0][0])[i] = 0u;

    // GRU1 biases (z,r folded; h kept split for reset_after), counted once via kh mask
    const float bm1  = (kh == 0) ? 1.0f : 0.0f;
    const float bz1  = (b1[j] + b1[768 + j]) * bm1;
    const float br1  = (b1[256 + j] + b1[1024 + j]) * bm1;
    const float bxh1 = b1[512 + j] * bm1;
    const float brh1 = b1[1280 + j] * bm1;
    // GRU2 biases, counted once via kq mask
    const float bm2  = (kq == 0) ? 1.0f : 0.0f;
    const float bz2  = (b2[c2] + b2[384 + c2]) * bm2;
    const float br2  = (b2[128 + c2] + b2[512 + c2]) * bm2;
    const float bxh2 = b2[256 + c2] * bm2;
    const float brh2 = b2[640 + c2] * bm2;

    // global weight bases (per thread column)
    const uint4* g1z = wp4 + G1Z_U4 + (kh * 20) * 256 + j;
    const uint4* g1r = wp4 + G1R_U4 + (kh * 20) * 256 + j;
    const uint4* g1h = wp4 + G1H_U4 + (kh * 20) * 256 + j;
    const uint4* g2z = wp4 + G2Z_U4 + (kq * 12) * 128 + c2;
    const uint4* g2r = wp4 + G2R_U4 + (kq * 12) * 128 + c2;
    const uint4* g2h = wp4 + G2H_U4 + (kq * 12) * 128 + c2;
    // LDS weight bases (lane-linear: gate stride 512, chunk stride 1536 uint4)
    const uint4* l2 = lw2 + tid;
    const uint4* l1 = lw1 + tid;

    __syncthreads();   // parked weights + zeros visible

    if (tid < FEAT) {
        float x0 = x[(size_t)row * TSEQ * FEAT + tid];
        float xb = __shfl_xor(x0, 1);
        if ((tid & 1) == 0) act1[0][tid >> 1] = pack2(x0, xb);
    }
    __syncthreads();

    float hp1 = 0.0f;   // h1 previous state, col j (redundant on the lane pair)
    float hp2 = 0.0f;   // h2 previous state, col c2 (redundant on the lane quad)

    for (int t = 0; t < TSEQ; ++t) {
        const int cur = t & 1, nb = cur ^ 1;

        // prefetch next x into registers (packed to LDS before the barrier)
        float xpre = 0.0f;
        if (t + 1 < TSEQ && tid < FEAT)
            xpre = x[(size_t)row * TSEQ * FEAT + (t + 1) * FEAT + tid];

        // ---------------- GRU1: reads act1[cur]; writes act1[nb] ----------------
        float az = bz1, ar = br1, aA = bxh1, aB = brh1;
        // x-part: chunks 0-1 from LDS (lane-linear), chunks 2-3 from global
        seg_pair<1536>(l1, l1 + 512, l1 + 1024,
                       &act1[cur][kh * 16], az, ar, aA);
        seg_pair<256>(g1z + 2 * 256, g1r + 2 * 256, g1h + 2 * 256,
                      &act1[cur][kh * 16 + 8], az, ar, aA);
        // h-part: 16 chunks from global (unchanged R3 path)
        seg3<256, 16>(g1z + 4 * 256, g1r + 4 * 256, g1h + 4 * 256,
                      &act1[cur][32 + kh * 64], az, ar, aB);
        az += __shfl_xor(az, 1);
        ar += __shfl_xor(ar, 1);
        aA += __shfl_xor(aA, 1);
        aB += __shfl_xor(aB, 1);
        {
            const float z  = sigmoid_f(az);
            const float rg = sigmoid_f(ar);
            const float hh = tanh_f(aA + rg * aB);
            const float hn = z * hp1 + (1.0f - z) * hh;
            hp1 = hn;
            const float hnb = __shfl_xor(hn, 2);   // partner column (2m+1) on lane 4m
            if ((tid & 3) == 0) {
                const unsigned int pk = pack2(hn, hnb);
                const int p = tid >> 2;                    // pair index 0..127
                act1[nb][32 + p] = pk;
                act1s[nb][(p >> 5) * 40 + (p & 31)] = pk;  // skewed replica for GRU2
            }
        }
        if (t + 1 < TSEQ && tid < FEAT) {
            float xb = __shfl_xor(xpre, 1);
            if ((tid & 1) == 0) act1[nb][tid >> 1] = pack2(xpre, xb);
        }
        __syncthreads();   // THE one barrier: act1[nb]/act1s[nb] (h1(t)) + x(t+1) visible

        // ---------------- GRU2: reads act1s[nb] h-part, act2[cur]; writes act2[nb] ----------------
        float az2 = bz2, ar2 = br2, aA2 = bxh2, aB2 = brh2;
        // h1-part: 8 chunks from global, act from skewed replica (bank-spread)
        seg3<128, 8>(g2z, g2r, g2h, &act1s[nb][kq * 40], az2, ar2, aA2);
        // h2-part: 4 chunks from LDS (lane-linear)
        seg3<1536, 4>(l2, l2 + 512, l2 + 1024,
                      &act2[cur][kq * 16], az2, ar2, aB2);
        az2 += __shfl_xor(az2, 1); az2 += __shfl_xor(az2, 2);
        ar2 += __shfl_xor(ar2, 1); ar2 += __shfl_xor(ar2, 2);
        aA2 += __shfl_xor(aA2, 1); aA2 += __shfl_xor(aA2, 2);
        aB2 += __shfl_xor(aB2, 1); aB2 += __shfl_xor(aB2, 2);
        {
            const float z2v = sigmoid_f(az2);
            const float rg2 = sigmoid_f(ar2);
            const float hh2 = tanh_f(aA2 + rg2 * aB2);
            const float hn2 = z2v * hp2 + (1.0f - z2v) * hh2;
            hp2 = hn2;
            const float hnb2 = __shfl_xor(hn2, 4); // partner column (2m+1) on lane 8m
            if ((tid & 7) == 0) act2[nb][tid >> 3] = pack2(hn2, hnb2);
        }
        // no second barrier: next step's barrier covers act2[nb] visibility;
        // all WAR hazards are buffer-separated (same discipline as proven kernel)
    }

    if ((tid & 3) == 0) h2fin[c2] = hp2;   // final h2 state, fp32
    __syncthreads();

    // ---------------- dense head: h2 -> 64 -> 32 -> 24 ----------------
    if (tid < 64) {
        float a = b3[tid];
        #pragma unroll 4
        for (int u = 0; u < NU2; ++u) a += h2fin[u] * w3[u * 64 + tid];
        d3[tid] = a;
    }
    __syncthreads();
    if (tid < 32) {
        float a = b4[tid];
        #pragma unroll 4
        for (int u = 0; u < 64; ++u) a += d3[u] * w4[u * 32 + tid];
        d4[tid] = a;
    }
    __syncthreads();
    if (tid < 24) {
        float a = b5[tid];
        #pragma unroll 4
        for (int u = 0; u < 32; ++u) a += d4[u] * w5[u * 24 + tid];
        out[(size_t)row * 24 + tid] = a;
    }
}

extern "C" void kernel_launch(void* const* d_in, const int* in_sizes, int n_in,
                              void* d_out, int out_size, void* d_ws, size_t ws_size,
                              hipStream_t stream) {
    (void)in_sizes; (void)n_in; (void)ws_size; (void)out_size;
    const float* x  = (const float*)d_in[0];
    const float* k1 = (const float*)d_in[1];
    const float* r1 = (const float*)d_in[2];
    const float* b1 = (const float*)d_in[3];
    const float* k2 = (const float*)d_in[4];
    const float* r2 = (const float*)d_in[5];
    const float* b2 = (const float*)d_in[6];
    const float* w3 = (const float*)d_in[7];
    const float* b3 = (const float*)d_in[8];
    const float* w4 = (const float*)d_in[9];
    const float* b4 = (const float*)d_in[10];
    const float* w5 = (const float*)d_in[11];
    const float* b5 = (const float*)d_in[12];
    float* out = (float*)d_out;

    // Opt in to >64 KB dynamic LDS (host-side, executes at capture time).
    static bool lds_attr_set = false;
    if (!lds_attr_set) {
        (void)hipFuncSetAttribute((const void*)gru_fused,
                                  hipFuncAttributeMaxDynamicSharedMemorySize,
                                  LDS_PARK_BYTES);
        lds_attr_set = true;
    }

    hipLaunchKernelGGL(pack_weights, dim3((TOTAL_H2 + 255) / 256), dim3(256), 0, stream,
                       k1, r1, k2, r2, (__half2*)d_ws);
    hipLaunchKernelGGL(gru_fused, dim3(BATCH), dim3(512), LDS_PARK_BYTES, stream,
                       x, b1, b2, w3, b3, w4, b4, w5, b5,
                       (const unsigned int*)d_ws, out);
}